// Round 4
// baseline (69.235 us; speedup 1.0000x reference)
//
#include <hip/hip_runtime.h>

// MixedActivation: x[1000000][48] fp32. Column c: (c%6)<3 -> x*x,
// else PReLU with slope prelu_a[(c%6)-3].
// Streaming op, 384 MB HBM traffic, memory-bound.
// R4: grid chosen so stride % 3 == 0 -> per-thread pattern key (i%3) is
// loop-invariant; slope/is-square hoisted out of the loop. Manual unroll-2
// for MLP. Nontemporal load/store kept (R3: +9%).

typedef float floatv4 __attribute__((ext_vector_type(4)));

__global__ __launch_bounds__(256)
void MixedActivation_kernel(const floatv4* __restrict__ x,
                            const float* __restrict__ a,
                            floatv4* __restrict__ out,
                            int n4) {
    const float a0 = a[0], a1 = a[1], a2 = a[2];
    const int stride = gridDim.x * blockDim.x;   // launcher guarantees %3==0
    int i = blockIdx.x * blockDim.x + threadIdx.x;

    // Pattern key for this thread — constant across iterations since
    // stride % 3 == 0. (4*i) % 6: i%3 = 0,1,2 -> base 0,4,2.
    const int t = i % 3;
    const int b = (t == 0) ? 0 : (t == 1) ? 4 : 2;

    float slope[4];
    bool  issq[4];
#pragma unroll
    for (int k = 0; k < 4; ++k) {
        int m = b + k;
        if (m >= 6) m -= 6;
        slope[k] = (m == 3) ? a0 : (m == 4) ? a1 : a2;
        issq[k]  = (m < 3);
    }

    // Unroll-2: two independent nt loads in flight per iteration.
    for (; i + stride < n4; i += 2 * stride) {
        floatv4 v0 = __builtin_nontemporal_load(&x[i]);
        floatv4 v1 = __builtin_nontemporal_load(&x[i + stride]);
        floatv4 r0, r1;
#pragma unroll
        for (int k = 0; k < 4; ++k) {
            const float p0 = fmaxf(v0[k], 0.0f) + slope[k] * fminf(v0[k], 0.0f);
            const float p1 = fmaxf(v1[k], 0.0f) + slope[k] * fminf(v1[k], 0.0f);
            r0[k] = issq[k] ? v0[k] * v0[k] : p0;
            r1[k] = issq[k] ? v1[k] * v1[k] : p1;
        }
        __builtin_nontemporal_store(r0, &out[i]);
        __builtin_nontemporal_store(r1, &out[i + stride]);
    }
    if (i < n4) {
        floatv4 v = __builtin_nontemporal_load(&x[i]);
        floatv4 r;
#pragma unroll
        for (int k = 0; k < 4; ++k) {
            const float p = fmaxf(v[k], 0.0f) + slope[k] * fminf(v[k], 0.0f);
            r[k] = issq[k] ? v[k] * v[k] : p;
        }
        __builtin_nontemporal_store(r, &out[i]);
    }
}

extern "C" void kernel_launch(void* const* d_in, const int* in_sizes, int n_in,
                              void* d_out, int out_size, void* d_ws, size_t ws_size,
                              hipStream_t stream) {
    const float* x = (const float*)d_in[0];
    const float* a = (const float*)d_in[1];
    float* out = (float*)d_out;

    const int n = out_size;        // 48,000,000 elements
    const int n4 = n / 4;          // 12,000,000 float4s

    const int block = 256;
    // 2046 blocks: stride = 2046*256 = 523776 float4s, divisible by 3
    // (pattern key loop-invariant) and ~8 blocks/CU (full occupancy).
    const int grid = 2046;

    MixedActivation_kernel<<<grid, block, 0, stream>>>(
        (const floatv4*)x, a, (floatv4*)out, n4);
}